// Round 11
// baseline (410.986 us; speedup 1.0000x reference)
//
#include <hip/hip_runtime.h>
#include <stdint.h>
#include <stddef.h>

typedef _Float16 half_t;
typedef _Float16 half4 __attribute__((ext_vector_type(4)));
typedef _Float16 half8 __attribute__((ext_vector_type(8)));

// ---------------------------------------------------------------------------
// JAX threefry2x32 (partitionable mode — verified: absmax 2.4e-4).
// ---------------------------------------------------------------------------
__host__ __device__ __forceinline__ uint32_t rotl32(uint32_t v, uint32_t r) {
  return (v << r) | (v >> (32u - r));
}

__host__ __device__ __forceinline__ void tf2x32(uint32_t k0, uint32_t k1,
                                                uint32_t x0, uint32_t x1,
                                                uint32_t& o0, uint32_t& o1) {
  uint32_t ks2 = k0 ^ k1 ^ 0x1BD11BDAu;
  x0 += k0; x1 += k1;
  x0 += x1; x1 = rotl32(x1, 13); x1 ^= x0;
  x0 += x1; x1 = rotl32(x1, 15); x1 ^= x0;
  x0 += x1; x1 = rotl32(x1, 26); x1 ^= x0;
  x0 += x1; x1 = rotl32(x1, 6);  x1 ^= x0;
  x0 += k1; x1 += ks2 + 1u;
  x0 += x1; x1 = rotl32(x1, 17); x1 ^= x0;
  x0 += x1; x1 = rotl32(x1, 29); x1 ^= x0;
  x0 += x1; x1 = rotl32(x1, 16); x1 ^= x0;
  x0 += x1; x1 = rotl32(x1, 24); x1 ^= x0;
  x0 += ks2; x1 += k0 + 2u;
  x0 += x1; x1 = rotl32(x1, 13); x1 ^= x0;
  x0 += x1; x1 = rotl32(x1, 15); x1 ^= x0;
  x0 += x1; x1 = rotl32(x1, 26); x1 ^= x0;
  x0 += x1; x1 = rotl32(x1, 6);  x1 ^= x0;
  x0 += k0; x1 += k1 + 3u;
  x0 += x1; x1 = rotl32(x1, 17); x1 ^= x0;
  x0 += x1; x1 = rotl32(x1, 29); x1 ^= x0;
  x0 += x1; x1 = rotl32(x1, 16); x1 ^= x0;
  x0 += x1; x1 = rotl32(x1, 24); x1 ^= x0;
  x0 += k1; x1 += ks2 + 4u;
  x0 += x1; x1 = rotl32(x1, 13); x1 ^= x0;
  x0 += x1; x1 = rotl32(x1, 15); x1 ^= x0;
  x0 += x1; x1 = rotl32(x1, 26); x1 ^= x0;
  x0 += x1; x1 = rotl32(x1, 6);  x1 ^= x0;
  x0 += ks2; x1 += k0 + 5u;
  o0 = x0; o1 = x1;
}

__device__ __forceinline__ bool tf_keep(uint32_t k0, uint32_t k1, uint32_t idx) {
  uint32_t o0, o1;
  tf2x32(k0, k1, 0u, idx, o0, o1);
  return ((o0 ^ o1) >> 31) == 0u;
}

// ---------------------------------------------------------------------------
// CSR build, chunk-major staging (unchanged).
// ---------------------------------------------------------------------------
#define CHUNK 4096
#define STASH 5120

__global__ __launch_bounds__(1024) void zero1024(uint32_t* __restrict__ p) {
  p[threadIdx.x] = 0u;
}

__global__ __launch_bounds__(256) void k4_binhist(const int* __restrict__ src,
                                                  const int* __restrict__ dst,
                                                  uint32_t* __restrict__ tbl,
                                                  uint32_t* __restrict__ gbcnt,
                                                  uint32_t* __restrict__ staging,
                                                  int E, int NB) {
  __shared__ uint32_t lcur[1024];
  __shared__ uint32_t ls[256];
  __shared__ uint32_t stage[CHUNK];
  int tid = threadIdx.x;
  for (int i = tid; i < NB; i += 256) lcur[i] = 0u;
  __syncthreads();
  int base = blockIdx.x * CHUNK;
  int end = min(base + CHUNK, E);
  uint32_t dv[16], sv[16];
  int m = 0;
  for (int i = base + tid; i < end; i += 256) {
    dv[m] = (uint32_t)dst[i];
    sv[m] = (uint32_t)src[i];
    ++m;
  }
  for (int q = 0; q < m; ++q) atomicAdd(&lcur[dv[q] >> 7], 1u);
  __syncthreads();
  uint32_t carry = 0u;
  for (int seg = 0; seg < 1024; seg += 256) {
    int i = seg + tid;
    uint32_t v = (i < NB) ? lcur[i] : 0u;
    ls[tid] = v;
    __syncthreads();
    for (int off = 1; off < 256; off <<= 1) {
      uint32_t t = (tid >= off) ? ls[tid - off] : 0u;
      __syncthreads();
      if (tid >= off) ls[tid] += t;
      __syncthreads();
    }
    uint32_t excl = carry + ls[tid] - v;
    if (i < NB) {
      tbl[(size_t)blockIdx.x * NB + i] = (excl << 16) | v;
      if (v) atomicAdd(&gbcnt[i], v);
      lcur[i] = excl;
    }
    carry += ls[255];
    __syncthreads();
  }
  for (int q = 0; q < m; ++q) {
    uint32_t d = dv[q];
    uint32_t p = atomicAdd(&lcur[d >> 7], 1u);
    stage[p] = ((d & 127u) << 17) | sv[q];
  }
  __syncthreads();
  int cnt_total = end - base;
  uint32_t* outp = staging + (size_t)blockIdx.x * CHUNK;
  for (int i = tid; i < cnt_total; i += 256) outp[i] = stage[i];
}

__global__ __launch_bounds__(1024) void k3_bscan(const uint32_t* __restrict__ gbcnt,
                                                 uint32_t* __restrict__ bbase, int NB) {
  __shared__ uint32_t s[1024];
  int i = threadIdx.x;
  uint32_t v = (i < NB) ? gbcnt[i] : 0u;
  s[i] = v;
  __syncthreads();
  for (int off = 1; off < 1024; off <<= 1) {
    uint32_t t = (i >= off) ? s[i - off] : 0u;
    __syncthreads();
    if (i >= off) s[i] += t;
    __syncthreads();
  }
  if (i < NB) bbase[i] = s[i] - v;
}

__global__ __launch_bounds__(256) void k5_fin(
    const uint32_t* __restrict__ staging, const uint32_t* __restrict__ tbl,
    const uint32_t* __restrict__ bbase, uint32_t* __restrict__ rowp,
    float* __restrict__ dinv, uint32_t* __restrict__ esrc,
    int n, int E, int NBLK, int NB) {
  __shared__ uint32_t lpak[1024];
  __shared__ uint32_t P[1025];
  __shared__ uint32_t ls[256];
  __shared__ uint32_t stash[STASH];
  __shared__ uint32_t lc[128];
  __shared__ uint32_t sc[128];
  __shared__ uint32_t lcur[128];
  int tid = threadIdx.x;
  int b = blockIdx.x;
  if (tid < 128) lc[tid] = 0u;
  uint32_t carry = 0u;
  for (int seg = 0; seg < 1024; seg += 256) {
    int i = seg + tid;
    uint32_t packed = (i < NBLK) ? tbl[(size_t)i * NB + b] : 0u;
    lpak[i] = packed;
    uint32_t v = packed & 0xFFFFu;
    ls[tid] = v;
    __syncthreads();
    for (int off = 1; off < 256; off <<= 1) {
      uint32_t t = (tid >= off) ? ls[tid - off] : 0u;
      __syncthreads();
      if (tid >= off) ls[tid] += t;
      __syncthreads();
    }
    P[i] = carry + ls[tid] - v;
    carry += ls[255];
    __syncthreads();
  }
  if (tid == 0) P[NBLK] = carry;
  __syncthreads();
  uint32_t total = P[NBLK];
  for (int i = tid; i < NBLK; i += 256) {
    uint32_t packed = lpak[i];
    uint32_t cnt = packed & 0xFFFFu;
    uint32_t loff = packed >> 16;
    uint32_t p = P[i];
    const uint32_t* run = staging + (size_t)i * CHUNK + loff;
    for (uint32_t t2 = 0; t2 < cnt; ++t2) {
      uint32_t e = run[t2];
      uint32_t q = p + t2;
      if (q < STASH) stash[q] = e;
      atomicAdd(&lc[e >> 17], 1u);
    }
  }
  __syncthreads();
  uint32_t myc = (tid < 128) ? lc[tid] : 0u;
  if (tid < 128) sc[tid] = myc;
  __syncthreads();
  for (int off = 1; off < 128; off <<= 1) {
    uint32_t t = (tid < 128 && tid >= off) ? sc[tid - off] : 0u;
    __syncthreads();
    if (tid < 128 && tid >= off) sc[tid] += t;
    __syncthreads();
  }
  uint32_t s = bbase[b];
  if (tid < 128) {
    uint32_t gstart = s + sc[tid] - myc;
    int node = (b << 7) + tid;
    if (node < n) {
      rowp[node] = gstart;
      dinv[node] = 1.0f / sqrtf((float)(myc + 1u));
    }
    lcur[tid] = gstart;
  }
  if (b == 0 && tid == 0) rowp[n] = (uint32_t)E;
  __syncthreads();
  uint32_t lim = total < (uint32_t)STASH ? total : (uint32_t)STASH;
  for (uint32_t q = tid; q < lim; q += 256) {
    uint32_t e = stash[q];
    uint32_t pos = atomicAdd(&lcur[e >> 17], 1u);
    esrc[pos] = e & 0x1FFFFu;
  }
  if (total > (uint32_t)STASH) {
    for (int i = tid; i < NBLK; i += 256) {
      uint32_t packed = lpak[i];
      uint32_t cnt = packed & 0xFFFFu;
      uint32_t loff = packed >> 16;
      uint32_t p = P[i];
      const uint32_t* run = staging + (size_t)i * CHUNK + loff;
      for (uint32_t t2 = 0; t2 < cnt; ++t2) {
        uint32_t q = p + t2;
        if (q >= (uint32_t)STASH) {
          uint32_t e = run[t2];
          uint32_t pos = atomicAdd(&lcur[e >> 17], 1u);
          esrc[pos] = e & 0x1FFFFu;
        }
      }
    }
  }
}

// ---------------------------------------------------------------------------
// GEMM: split-slab fp16 out (unchanged).
// ---------------------------------------------------------------------------
__global__ __launch_bounds__(256) void gemm_n64_k32(
    const float* __restrict__ X, const float* __restrict__ W,
    const float* __restrict__ dinv, half_t* __restrict__ out16, int n) {
  __shared__ float Ws[64 * 32];
  __shared__ float Xs[32 * 68];
  int tid = threadIdx.x;
  {
    const float4* Wv = (const float4*)W;
    float4* Wsv = (float4*)Ws;
    Wsv[tid] = Wv[tid];
    Wsv[tid + 256] = Wv[tid + 256];
  }
  int row0 = blockIdx.x * 32;
  {
    const float4* Xv = (const float4*)(X + (size_t)row0 * 64);
    int lim = (n - row0) * 16;
    float4 z = make_float4(0.f, 0.f, 0.f, 0.f);
    int i0 = tid, i1 = tid + 256;
    float4 v0 = (i0 < lim) ? Xv[i0] : z;
    float4 v1 = (i1 < lim) ? Xv[i1] : z;
    *(float4*)(Xs + (i0 >> 4) * 68 + ((i0 & 15) << 2)) = v0;
    *(float4*)(Xs + (i1 >> 4) * 68 + ((i1 & 15) << 2)) = v1;
  }
  __syncthreads();
  int r = tid >> 3;
  int c4 = (tid & 7) << 2;
  int row = row0 + r;
  if (row >= n) return;
  float4 acc = make_float4(0.f, 0.f, 0.f, 0.f);
#pragma unroll
  for (int k = 0; k < 64; k += 4) {
    float4 xv = *(const float4*)(Xs + r * 68 + k);
    float4 w0 = *(const float4*)(Ws + (k + 0) * 32 + c4);
    float4 w1 = *(const float4*)(Ws + (k + 1) * 32 + c4);
    float4 w2 = *(const float4*)(Ws + (k + 2) * 32 + c4);
    float4 w3 = *(const float4*)(Ws + (k + 3) * 32 + c4);
    acc.x = fmaf(xv.x, w0.x, acc.x); acc.y = fmaf(xv.x, w0.y, acc.y);
    acc.z = fmaf(xv.x, w0.z, acc.z); acc.w = fmaf(xv.x, w0.w, acc.w);
    acc.x = fmaf(xv.y, w1.x, acc.x); acc.y = fmaf(xv.y, w1.y, acc.y);
    acc.z = fmaf(xv.y, w1.z, acc.z); acc.w = fmaf(xv.y, w1.w, acc.w);
    acc.x = fmaf(xv.z, w2.x, acc.x); acc.y = fmaf(xv.z, w2.y, acc.y);
    acc.z = fmaf(xv.z, w2.z, acc.z); acc.w = fmaf(xv.z, w2.w, acc.w);
    acc.x = fmaf(xv.w, w3.x, acc.x); acc.y = fmaf(xv.w, w3.y, acc.y);
    acc.z = fmaf(xv.w, w3.z, acc.z); acc.w = fmaf(xv.w, w3.w, acc.w);
  }
  float dj = dinv[row];
  half4 h;
  h.x = (half_t)(acc.x * dj); h.y = (half_t)(acc.y * dj);
  h.z = (half_t)(acc.z * dj); h.w = (half_t)(acc.w * dj);
  size_t slab = (size_t)(c4 >> 4) * ((size_t)n * 16);
  *(half4*)(out16 + slab + (size_t)row * 16 + (c4 & 15)) = h;
}

// ---------------------------------------------------------------------------
// GEMM: out[n,64] = dropout(celu(X[n,32] @ W[32,64] + b))  (unchanged).
// ---------------------------------------------------------------------------
__global__ __launch_bounds__(256) void gemm_k32_n64_act(
    const float* __restrict__ X, const float* __restrict__ W,
    const float* __restrict__ bias, float* __restrict__ out,
    uint32_t k0, uint32_t k1, int n) {
  __shared__ float Ws[32 * 64];
  __shared__ float Xs[16 * 36];
  int tid = threadIdx.x;
  {
    const float4* Wv = (const float4*)W;
    float4* Wsv = (float4*)Ws;
    Wsv[tid] = Wv[tid];
    Wsv[tid + 256] = Wv[tid + 256];
  }
  int row0 = blockIdx.x * 16;
  if (tid < 128) {
    const float4* Xv = (const float4*)(X + (size_t)row0 * 32);
    int lim = (n - row0) * 8;
    float4 z = make_float4(0.f, 0.f, 0.f, 0.f);
    float4 v = (tid < lim) ? Xv[tid] : z;
    *(float4*)(Xs + (tid >> 3) * 36 + ((tid & 7) << 2)) = v;
  }
  __syncthreads();
  int r = tid >> 4;
  int c4 = (tid & 15) << 2;
  int row = row0 + r;
  if (row >= n) return;
  float4 acc = make_float4(0.f, 0.f, 0.f, 0.f);
#pragma unroll
  for (int k = 0; k < 32; k += 4) {
    float4 xv = *(const float4*)(Xs + r * 36 + k);
    float4 w0 = *(const float4*)(Ws + (k + 0) * 64 + c4);
    float4 w1 = *(const float4*)(Ws + (k + 1) * 64 + c4);
    float4 w2 = *(const float4*)(Ws + (k + 2) * 64 + c4);
    float4 w3 = *(const float4*)(Ws + (k + 3) * 64 + c4);
    acc.x = fmaf(xv.x, w0.x, acc.x); acc.y = fmaf(xv.x, w0.y, acc.y);
    acc.z = fmaf(xv.x, w0.z, acc.z); acc.w = fmaf(xv.x, w0.w, acc.w);
    acc.x = fmaf(xv.y, w1.x, acc.x); acc.y = fmaf(xv.y, w1.y, acc.y);
    acc.z = fmaf(xv.y, w1.z, acc.z); acc.w = fmaf(xv.y, w1.w, acc.w);
    acc.x = fmaf(xv.z, w2.x, acc.x); acc.y = fmaf(xv.z, w2.y, acc.y);
    acc.z = fmaf(xv.z, w2.z, acc.z); acc.w = fmaf(xv.z, w2.w, acc.w);
    acc.x = fmaf(xv.w, w3.x, acc.x); acc.y = fmaf(xv.w, w3.y, acc.y);
    acc.z = fmaf(xv.w, w3.z, acc.z); acc.w = fmaf(xv.w, w3.w, acc.w);
  }
  float4 bv = *(const float4*)(bias + c4);
  float vv[4] = {acc.x + bv.x, acc.y + bv.y, acc.z + bv.z, acc.w + bv.w};
  uint32_t base = (uint32_t)row * 64u + (uint32_t)c4;
#pragma unroll
  for (int q = 0; q < 4; ++q) {
    float v = vv[q];
    v = v > 0.f ? v : expm1f(v);
    vv[q] = tf_keep(k0, k1, base + q) ? v * 2.f : 0.f;
  }
  *(float4*)(out + (size_t)row * 64 + c4) = make_float4(vv[0], vv[1], vv[2], vv[3]);
}

// ---------------------------------------------------------------------------
// Gather-reduce v5: split slabs + LDS index staging + half8 row loads.
// Block: 8 dsts x 16 dims (one slab, XCD-affine cg as before). The block's
// 8 dsts own contiguous esrc range [rowp[j0], rowp[j0+8}) -> one coalesced
// copy to LDS; per-lane ds_read replaces per-edge ds_bpermute chains.
// Lane: eslot = l>>1 (16 edges in flight), chunk = l&1 (half8 = 8 dims).
// Single predicated edge loop (no remainder path).
// ---------------------------------------------------------------------------
#define ECAP 6144

__global__ __launch_bounds__(256) void gather_fin(
    const half_t* __restrict__ hs, const uint32_t* __restrict__ rowp,
    const uint32_t* __restrict__ esrc, const float* __restrict__ dinv,
    const float* __restrict__ bias, float* __restrict__ outf,
    half_t* __restrict__ outh, int n, int mode, uint32_t k0, uint32_t k1,
    float fone) {
  __shared__ uint32_t ldsidx[ECAP];
  __shared__ __align__(16) float ldsred[8 * 16];
  uint32_t bid = blockIdx.x;
  int cg = (int)((bid >> 2) & 1u);
  int dstblk = (int)((bid >> 3) * 4u + (bid & 3u));
  int tid = threadIdx.x;
  int j0 = dstblk * 8;
  if (j0 >= n) return;
  int jend = min(j0 + 8, n);
  uint32_t e0blk = rowp[j0];
  uint32_t esz = rowp[jend] - e0blk;
  bool fits = esz <= (uint32_t)ECAP;
  if (fits) {
    for (uint32_t i = (uint32_t)tid; i < esz; i += 256u)
      ldsidx[i] = esrc[e0blk + i];
  }
  __syncthreads();
  int g = tid >> 5;
  int j = j0 + g;
  int l = tid & 31;
  int eslot = l >> 1;
  int chunk = l & 1;
  const half_t* slab = hs + (size_t)cg * ((size_t)n * 16);
  float acc[8] = {0.f, 0.f, 0.f, 0.f, 0.f, 0.f, 0.f, 0.f};
  if (j < n) {
    uint32_t e0 = rowp[j], e1 = rowp[j + 1];
    uint32_t deg = e1 - e0;
    uint32_t eloc = e0 - e0blk;
    const half_t* hp = slab + (size_t)(chunk << 3);
    if (fits) {
      for (uint32_t e = (uint32_t)eslot; e < deg; e += 16u) {
        uint32_t idx = ldsidx[eloc + e];
        const half8 v = *(const half8*)(hp + ((size_t)idx << 4));
#pragma unroll
        for (int q = 0; q < 8; ++q) acc[q] = fmaf((float)v[q], fone, acc[q]);
      }
    } else {
      for (uint32_t e = (uint32_t)eslot; e < deg; e += 16u) {
        uint32_t idx = esrc[e0 + e];
        const half8 v = *(const half8*)(hp + ((size_t)idx << 4));
#pragma unroll
        for (int q = 0; q < 8; ++q) acc[q] = fmaf((float)v[q], fone, acc[q]);
      }
    }
  }
  // reduce across 16 eslots (lane bits 1..4)
#pragma unroll
  for (int m = 2; m <= 16; m <<= 1) {
#pragma unroll
    for (int q = 0; q < 8; ++q) acc[q] += __shfl_xor(acc[q], m);
  }
  // lanes 0/1 of each group hold dims [0,8) / [8,16): park in LDS, fan out
  if (l < 2) {
    *(float4*)(&ldsred[(g << 4) + (chunk << 3) + 0]) =
        make_float4(acc[0], acc[1], acc[2], acc[3]);
    *(float4*)(&ldsred[(g << 4) + (chunk << 3) + 4]) =
        make_float4(acc[4], acc[5], acc[6], acc[7]);
  }
  __builtin_amdgcn_wave_barrier();
  if (l >= 16 || j >= n) return;
  float sum = ldsred[(g << 4) + l];
  sum += (float)slab[(size_t)j * 16 + l];  // self-loop (already dinv-scaled)
  int c = (cg << 4) | l;
  float dj = dinv[j];
  float v = dj * sum;
  if (mode == 1) {
    v += bias[c];
    v = v > 0.f ? v : expm1f(v);
    outf[(size_t)j * 32 + c] = v;
  } else if (mode == 3) {
    v += bias[c];
    v = v > 0.f ? v : expm1f(v);
    v = tf_keep(k0, k1, (uint32_t)(j * 32 + c)) ? v * 2.f : 0.f;
    v *= dj;
    outh[(size_t)cg * ((size_t)n * 16) + (size_t)j * 16 + l] = (half_t)v;
  } else {
    outf[(size_t)j * 32 + c] = v;
  }
}

// ---------------------------------------------------------------------------
extern "C" void kernel_launch(void* const* d_in, const int* in_sizes, int n_in,
                              void* d_out, int out_size, void* d_ws, size_t ws_size,
                              hipStream_t stream) {
  const float* x  = (const float*)d_in[0];
  const int*   ei = (const int*)d_in[1];
  const float* W1 = (const float*)d_in[2];
  const float* b1 = (const float*)d_in[3];
  const float* W2 = (const float*)d_in[4];
  const float* b2 = (const float*)d_in[5];
  const float* W3 = (const float*)d_in[6];
  const float* b3 = (const float*)d_in[7];
  float* out = (float*)d_out;

  const int n = in_sizes[0] / 64;
  const int E = in_sizes[1] / 2;
  const int* src = ei;
  const int* dst = ei + E;

  char* ws = (char*)d_ws;
  size_t off = 0;
  auto alloc = [&](size_t bytes) {
    void* p = ws + off;
    off = (off + bytes + 255) & ~(size_t)255;
    return p;
  };
  float*    A32   = (float*)alloc((size_t)n * 32 * 4);  // gather2 out / gemm2 in; aliased tbl
  float*    C     = (float*)alloc((size_t)n * 64 * 4);  // gemm2 out; aliased staging
  half_t*   A16   = (half_t*)alloc((size_t)n * 32 * 2); // split-slab fp16 table
  half_t*   B16   = (half_t*)alloc((size_t)n * 32 * 2); // split-slab fp16 table
  float*    dinv  = (float*)alloc((size_t)n * 4);
  uint32_t* rowp  = (uint32_t*)alloc((size_t)(n + 1) * 4);
  uint32_t* esrc  = (uint32_t*)alloc((size_t)E * 4);
  uint32_t* gbcnt = (uint32_t*)alloc(1024 * 4);
  uint32_t* bbase = (uint32_t*)alloc(1024 * 4);
  uint32_t* staging = (uint32_t*)C;    // C dead until layer 2
  uint32_t* tbl     = (uint32_t*)A32;  // A32 dead until gather2
  (void)ws_size; (void)n_in; (void)out_size;

  uint32_t k1a, k1b, k2a, k2b;
  tf2x32(0u, 42u, 0u, 0u, k1a, k1b);
  tf2x32(0u, 42u, 0u, 1u, k2a, k2b);

  const int NB   = (n + 127) >> 7;
  const int NBLK = (E + CHUNK - 1) / CHUNK;
  const int NDB  = (n + 7) / 8;                 // dst blocks (8 nodes each)
  const int gV2  = 8 * ((NDB + 3) / 4);         // x2 column groups, XCD-affine
  const int gG1  = (n + 31) / 32;
  const int gG2  = (n + 15) / 16;
  dim3 blk(256);

  // ---- CSR build ----
  zero1024<<<1, dim3(1024), 0, stream>>>(gbcnt);
  k4_binhist<<<NBLK, blk, 0, stream>>>(src, dst, tbl, gbcnt, staging, E, NB);
  k3_bscan<<<1, dim3(1024), 0, stream>>>(gbcnt, bbase, NB);
  k5_fin<<<NB, blk, 0, stream>>>(staging, tbl, bbase, rowp, dinv, esrc, n, E, NBLK, NB);

  // ---- layer 1: A16 = fp16(dinv*(x@W1)) [split]; gather -> B16 [split] ----
  gemm_n64_k32<<<gG1, blk, 0, stream>>>(x, W1, dinv, A16, n);
  gather_fin<<<gV2, blk, 0, stream>>>(A16, rowp, esrc, dinv, b1, nullptr, B16, n, 3, k1a, k1b, 1.0f);

  // ---- layer 2: gather(B16) -> A32 (fp32 row-major); gemm2 -> C ----
  gather_fin<<<gV2, blk, 0, stream>>>(B16, rowp, esrc, dinv, nullptr, A32, nullptr, n, 0, 0u, 0u, 1.0f);
  gemm_k32_n64_act<<<gG2, blk, 0, stream>>>(A32, W2, b2, C, k2a, k2b, n);

  // ---- layer 3: A16 = fp16(dinv*(C@W3)) [split]; gather -> out (fp32) ----
  gemm_n64_k32<<<gG1, blk, 0, stream>>>(C, W3, dinv, A16, n);
  gather_fin<<<gV2, blk, 0, stream>>>(A16, rowp, esrc, dinv, b3, out, nullptr, n, 1, 0u, 0u, 1.0f);
}

// Round 12
// 334.469 us; speedup vs baseline: 1.2288x; 1.2288x over previous
//
#include <hip/hip_runtime.h>
#include <stdint.h>
#include <stddef.h>

typedef _Float16 half_t;
typedef _Float16 half4 __attribute__((ext_vector_type(4)));
typedef _Float16 half8 __attribute__((ext_vector_type(8)));

// ---------------------------------------------------------------------------
// JAX threefry2x32 (partitionable mode — verified: absmax 2.4e-4).
// ---------------------------------------------------------------------------
__host__ __device__ __forceinline__ uint32_t rotl32(uint32_t v, uint32_t r) {
  return (v << r) | (v >> (32u - r));
}

__host__ __device__ __forceinline__ void tf2x32(uint32_t k0, uint32_t k1,
                                                uint32_t x0, uint32_t x1,
                                                uint32_t& o0, uint32_t& o1) {
  uint32_t ks2 = k0 ^ k1 ^ 0x1BD11BDAu;
  x0 += k0; x1 += k1;
  x0 += x1; x1 = rotl32(x1, 13); x1 ^= x0;
  x0 += x1; x1 = rotl32(x1, 15); x1 ^= x0;
  x0 += x1; x1 = rotl32(x1, 26); x1 ^= x0;
  x0 += x1; x1 = rotl32(x1, 6);  x1 ^= x0;
  x0 += k1; x1 += ks2 + 1u;
  x0 += x1; x1 = rotl32(x1, 17); x1 ^= x0;
  x0 += x1; x1 = rotl32(x1, 29); x1 ^= x0;
  x0 += x1; x1 = rotl32(x1, 16); x1 ^= x0;
  x0 += x1; x1 = rotl32(x1, 24); x1 ^= x0;
  x0 += ks2; x1 += k0 + 2u;
  x0 += x1; x1 = rotl32(x1, 13); x1 ^= x0;
  x0 += x1; x1 = rotl32(x1, 15); x1 ^= x0;
  x0 += x1; x1 = rotl32(x1, 26); x1 ^= x0;
  x0 += x1; x1 = rotl32(x1, 6);  x1 ^= x0;
  x0 += k0; x1 += k1 + 3u;
  x0 += x1; x1 = rotl32(x1, 17); x1 ^= x0;
  x0 += x1; x1 = rotl32(x1, 29); x1 ^= x0;
  x0 += x1; x1 = rotl32(x1, 16); x1 ^= x0;
  x0 += x1; x1 = rotl32(x1, 24); x1 ^= x0;
  x0 += k1; x1 += ks2 + 4u;
  x0 += x1; x1 = rotl32(x1, 13); x1 ^= x0;
  x0 += x1; x1 = rotl32(x1, 15); x1 ^= x0;
  x0 += x1; x1 = rotl32(x1, 26); x1 ^= x0;
  x0 += x1; x1 = rotl32(x1, 6);  x1 ^= x0;
  x0 += ks2; x1 += k0 + 5u;
  o0 = x0; o1 = x1;
}

__device__ __forceinline__ bool tf_keep(uint32_t k0, uint32_t k1, uint32_t idx) {
  uint32_t o0, o1;
  tf2x32(k0, k1, 0u, idx, o0, o1);
  return ((o0 ^ o1) >> 31) == 0u;
}

// ---------------------------------------------------------------------------
// CSR build, chunk-major staging (unchanged).
// ---------------------------------------------------------------------------
#define CHUNK 4096
#define STASH 5120

__global__ __launch_bounds__(1024) void zero1024(uint32_t* __restrict__ p) {
  p[threadIdx.x] = 0u;
}

__global__ __launch_bounds__(256) void k4_binhist(const int* __restrict__ src,
                                                  const int* __restrict__ dst,
                                                  uint32_t* __restrict__ tbl,
                                                  uint32_t* __restrict__ gbcnt,
                                                  uint32_t* __restrict__ staging,
                                                  int E, int NB) {
  __shared__ uint32_t lcur[1024];
  __shared__ uint32_t ls[256];
  __shared__ uint32_t stage[CHUNK];
  int tid = threadIdx.x;
  for (int i = tid; i < NB; i += 256) lcur[i] = 0u;
  __syncthreads();
  int base = blockIdx.x * CHUNK;
  int end = min(base + CHUNK, E);
  uint32_t dv[16], sv[16];
  int m = 0;
  for (int i = base + tid; i < end; i += 256) {
    dv[m] = (uint32_t)dst[i];
    sv[m] = (uint32_t)src[i];
    ++m;
  }
  for (int q = 0; q < m; ++q) atomicAdd(&lcur[dv[q] >> 7], 1u);
  __syncthreads();
  uint32_t carry = 0u;
  for (int seg = 0; seg < 1024; seg += 256) {
    int i = seg + tid;
    uint32_t v = (i < NB) ? lcur[i] : 0u;
    ls[tid] = v;
    __syncthreads();
    for (int off = 1; off < 256; off <<= 1) {
      uint32_t t = (tid >= off) ? ls[tid - off] : 0u;
      __syncthreads();
      if (tid >= off) ls[tid] += t;
      __syncthreads();
    }
    uint32_t excl = carry + ls[tid] - v;
    if (i < NB) {
      tbl[(size_t)blockIdx.x * NB + i] = (excl << 16) | v;
      if (v) atomicAdd(&gbcnt[i], v);
      lcur[i] = excl;
    }
    carry += ls[255];
    __syncthreads();
  }
  for (int q = 0; q < m; ++q) {
    uint32_t d = dv[q];
    uint32_t p = atomicAdd(&lcur[d >> 7], 1u);
    stage[p] = ((d & 127u) << 17) | sv[q];
  }
  __syncthreads();
  int cnt_total = end - base;
  uint32_t* outp = staging + (size_t)blockIdx.x * CHUNK;
  for (int i = tid; i < cnt_total; i += 256) outp[i] = stage[i];
}

__global__ __launch_bounds__(1024) void k3_bscan(const uint32_t* __restrict__ gbcnt,
                                                 uint32_t* __restrict__ bbase, int NB) {
  __shared__ uint32_t s[1024];
  int i = threadIdx.x;
  uint32_t v = (i < NB) ? gbcnt[i] : 0u;
  s[i] = v;
  __syncthreads();
  for (int off = 1; off < 1024; off <<= 1) {
    uint32_t t = (i >= off) ? s[i - off] : 0u;
    __syncthreads();
    if (i >= off) s[i] += t;
    __syncthreads();
  }
  if (i < NB) bbase[i] = s[i] - v;
}

__global__ __launch_bounds__(256) void k5_fin(
    const uint32_t* __restrict__ staging, const uint32_t* __restrict__ tbl,
    const uint32_t* __restrict__ bbase, uint32_t* __restrict__ rowp,
    float* __restrict__ dinv, uint32_t* __restrict__ esrc,
    int n, int E, int NBLK, int NB) {
  __shared__ uint32_t lpak[1024];
  __shared__ uint32_t P[1025];
  __shared__ uint32_t ls[256];
  __shared__ uint32_t stash[STASH];
  __shared__ uint32_t lc[128];
  __shared__ uint32_t sc[128];
  __shared__ uint32_t lcur[128];
  int tid = threadIdx.x;
  int b = blockIdx.x;
  if (tid < 128) lc[tid] = 0u;
  uint32_t carry = 0u;
  for (int seg = 0; seg < 1024; seg += 256) {
    int i = seg + tid;
    uint32_t packed = (i < NBLK) ? tbl[(size_t)i * NB + b] : 0u;
    lpak[i] = packed;
    uint32_t v = packed & 0xFFFFu;
    ls[tid] = v;
    __syncthreads();
    for (int off = 1; off < 256; off <<= 1) {
      uint32_t t = (tid >= off) ? ls[tid - off] : 0u;
      __syncthreads();
      if (tid >= off) ls[tid] += t;
      __syncthreads();
    }
    P[i] = carry + ls[tid] - v;
    carry += ls[255];
    __syncthreads();
  }
  if (tid == 0) P[NBLK] = carry;
  __syncthreads();
  uint32_t total = P[NBLK];
  for (int i = tid; i < NBLK; i += 256) {
    uint32_t packed = lpak[i];
    uint32_t cnt = packed & 0xFFFFu;
    uint32_t loff = packed >> 16;
    uint32_t p = P[i];
    const uint32_t* run = staging + (size_t)i * CHUNK + loff;
    for (uint32_t t2 = 0; t2 < cnt; ++t2) {
      uint32_t e = run[t2];
      uint32_t q = p + t2;
      if (q < STASH) stash[q] = e;
      atomicAdd(&lc[e >> 17], 1u);
    }
  }
  __syncthreads();
  uint32_t myc = (tid < 128) ? lc[tid] : 0u;
  if (tid < 128) sc[tid] = myc;
  __syncthreads();
  for (int off = 1; off < 128; off <<= 1) {
    uint32_t t = (tid < 128 && tid >= off) ? sc[tid - off] : 0u;
    __syncthreads();
    if (tid < 128 && tid >= off) sc[tid] += t;
    __syncthreads();
  }
  uint32_t s = bbase[b];
  if (tid < 128) {
    uint32_t gstart = s + sc[tid] - myc;
    int node = (b << 7) + tid;
    if (node < n) {
      rowp[node] = gstart;
      dinv[node] = 1.0f / sqrtf((float)(myc + 1u));
    }
    lcur[tid] = gstart;
  }
  if (b == 0 && tid == 0) rowp[n] = (uint32_t)E;
  __syncthreads();
  uint32_t lim = total < (uint32_t)STASH ? total : (uint32_t)STASH;
  for (uint32_t q = tid; q < lim; q += 256) {
    uint32_t e = stash[q];
    uint32_t pos = atomicAdd(&lcur[e >> 17], 1u);
    esrc[pos] = e & 0x1FFFFu;
  }
  if (total > (uint32_t)STASH) {
    for (int i = tid; i < NBLK; i += 256) {
      uint32_t packed = lpak[i];
      uint32_t cnt = packed & 0xFFFFu;
      uint32_t loff = packed >> 16;
      uint32_t p = P[i];
      const uint32_t* run = staging + (size_t)i * CHUNK + loff;
      for (uint32_t t2 = 0; t2 < cnt; ++t2) {
        uint32_t q = p + t2;
        if (q >= (uint32_t)STASH) {
          uint32_t e = run[t2];
          uint32_t pos = atomicAdd(&lcur[e >> 17], 1u);
          esrc[pos] = e & 0x1FFFFu;
        }
      }
    }
  }
}

// ---------------------------------------------------------------------------
// GEMM: out16[n,32] = fp16( dinv[row] * (X[n,64] @ W[64,32]) )  (row-major).
// ---------------------------------------------------------------------------
__global__ __launch_bounds__(256) void gemm_n64_k32(
    const float* __restrict__ X, const float* __restrict__ W,
    const float* __restrict__ dinv, half_t* __restrict__ out16, int n) {
  __shared__ float Ws[64 * 32];
  __shared__ float Xs[32 * 68];
  int tid = threadIdx.x;
  {
    const float4* Wv = (const float4*)W;
    float4* Wsv = (float4*)Ws;
    Wsv[tid] = Wv[tid];
    Wsv[tid + 256] = Wv[tid + 256];
  }
  int row0 = blockIdx.x * 32;
  {
    const float4* Xv = (const float4*)(X + (size_t)row0 * 64);
    int lim = (n - row0) * 16;
    float4 z = make_float4(0.f, 0.f, 0.f, 0.f);
    int i0 = tid, i1 = tid + 256;
    float4 v0 = (i0 < lim) ? Xv[i0] : z;
    float4 v1 = (i1 < lim) ? Xv[i1] : z;
    *(float4*)(Xs + (i0 >> 4) * 68 + ((i0 & 15) << 2)) = v0;
    *(float4*)(Xs + (i1 >> 4) * 68 + ((i1 & 15) << 2)) = v1;
  }
  __syncthreads();
  int r = tid >> 3;
  int c4 = (tid & 7) << 2;
  int row = row0 + r;
  if (row >= n) return;
  float4 acc = make_float4(0.f, 0.f, 0.f, 0.f);
#pragma unroll
  for (int k = 0; k < 64; k += 4) {
    float4 xv = *(const float4*)(Xs + r * 68 + k);
    float4 w0 = *(const float4*)(Ws + (k + 0) * 32 + c4);
    float4 w1 = *(const float4*)(Ws + (k + 1) * 32 + c4);
    float4 w2 = *(const float4*)(Ws + (k + 2) * 32 + c4);
    float4 w3 = *(const float4*)(Ws + (k + 3) * 32 + c4);
    acc.x = fmaf(xv.x, w0.x, acc.x); acc.y = fmaf(xv.x, w0.y, acc.y);
    acc.z = fmaf(xv.x, w0.z, acc.z); acc.w = fmaf(xv.x, w0.w, acc.w);
    acc.x = fmaf(xv.y, w1.x, acc.x); acc.y = fmaf(xv.y, w1.y, acc.y);
    acc.z = fmaf(xv.y, w1.z, acc.z); acc.w = fmaf(xv.y, w1.w, acc.w);
    acc.x = fmaf(xv.z, w2.x, acc.x); acc.y = fmaf(xv.z, w2.y, acc.y);
    acc.z = fmaf(xv.z, w2.z, acc.z); acc.w = fmaf(xv.z, w2.w, acc.w);
    acc.x = fmaf(xv.w, w3.x, acc.x); acc.y = fmaf(xv.w, w3.y, acc.y);
    acc.z = fmaf(xv.w, w3.z, acc.z); acc.w = fmaf(xv.w, w3.w, acc.w);
  }
  float dj = dinv[row];
  half4 h;
  h.x = (half_t)(acc.x * dj); h.y = (half_t)(acc.y * dj);
  h.z = (half_t)(acc.z * dj); h.w = (half_t)(acc.w * dj);
  *(half4*)(out16 + (size_t)row * 32 + c4) = h;
}

// ---------------------------------------------------------------------------
// GEMM: out[n,64] = dropout(celu(X[n,32] @ W[32,64] + b))  (fp32 in/out).
// ---------------------------------------------------------------------------
__global__ __launch_bounds__(256) void gemm_k32_n64_act(
    const float* __restrict__ X, const float* __restrict__ W,
    const float* __restrict__ bias, float* __restrict__ out,
    uint32_t k0, uint32_t k1, int n) {
  __shared__ float Ws[32 * 64];
  __shared__ float Xs[16 * 36];
  int tid = threadIdx.x;
  {
    const float4* Wv = (const float4*)W;
    float4* Wsv = (float4*)Ws;
    Wsv[tid] = Wv[tid];
    Wsv[tid + 256] = Wv[tid + 256];
  }
  int row0 = blockIdx.x * 16;
  if (tid < 128) {
    const float4* Xv = (const float4*)(X + (size_t)row0 * 32);
    int lim = (n - row0) * 8;
    float4 z = make_float4(0.f, 0.f, 0.f, 0.f);
    float4 v = (tid < lim) ? Xv[tid] : z;
    *(float4*)(Xs + (tid >> 3) * 36 + ((tid & 7) << 2)) = v;
  }
  __syncthreads();
  int r = tid >> 4;
  int c4 = (tid & 15) << 2;
  int row = row0 + r;
  if (row >= n) return;
  float4 acc = make_float4(0.f, 0.f, 0.f, 0.f);
#pragma unroll
  for (int k = 0; k < 32; k += 4) {
    float4 xv = *(const float4*)(Xs + r * 36 + k);
    float4 w0 = *(const float4*)(Ws + (k + 0) * 64 + c4);
    float4 w1 = *(const float4*)(Ws + (k + 1) * 64 + c4);
    float4 w2 = *(const float4*)(Ws + (k + 2) * 64 + c4);
    float4 w3 = *(const float4*)(Ws + (k + 3) * 64 + c4);
    acc.x = fmaf(xv.x, w0.x, acc.x); acc.y = fmaf(xv.x, w0.y, acc.y);
    acc.z = fmaf(xv.x, w0.z, acc.z); acc.w = fmaf(xv.x, w0.w, acc.w);
    acc.x = fmaf(xv.y, w1.x, acc.x); acc.y = fmaf(xv.y, w1.y, acc.y);
    acc.z = fmaf(xv.y, w1.z, acc.z); acc.w = fmaf(xv.y, w1.w, acc.w);
    acc.x = fmaf(xv.z, w2.x, acc.x); acc.y = fmaf(xv.z, w2.y, acc.y);
    acc.z = fmaf(xv.z, w2.z, acc.z); acc.w = fmaf(xv.z, w2.w, acc.w);
    acc.x = fmaf(xv.w, w3.x, acc.x); acc.y = fmaf(xv.w, w3.y, acc.y);
    acc.z = fmaf(xv.w, w3.z, acc.z); acc.w = fmaf(xv.w, w3.w, acc.w);
  }
  float4 bv = *(const float4*)(bias + c4);
  float vv[4] = {acc.x + bv.x, acc.y + bv.y, acc.z + bv.z, acc.w + bv.w};
  uint32_t base = (uint32_t)row * 64u + (uint32_t)c4;
#pragma unroll
  for (int q = 0; q < 4; ++q) {
    float v = vv[q];
    v = v > 0.f ? v : expm1f(v);
    vv[q] = tf_keep(k0, k1, base + q) ? v * 2.f : 0.f;
  }
  *(float4*)(out + (size_t)row * 64 + c4) = make_float4(vv[0], vv[1], vv[2], vv[3]);
}

// ---------------------------------------------------------------------------
// Gather-reduce v6: R8 structure (row-major fp16 table, 64 B rows) with
// half8 (16 B) loads — 4 lanes/row instead of 8 -> loads+shuffles per edge
// halved vs R8. Lane: eslot = l>>2 (8 edge slots), chunk = l&3 (8 dims).
// Epilogue fan-out via 1 KB LDS park (groups stay within one wave).
// ---------------------------------------------------------------------------
__global__ __launch_bounds__(256) void gather_fin(
    const half_t* __restrict__ hs, const uint32_t* __restrict__ rowp,
    const uint32_t* __restrict__ esrc, const float* __restrict__ dinv,
    const float* __restrict__ bias, float* __restrict__ outf,
    half_t* __restrict__ outh, int n, int mode, uint32_t k0, uint32_t k1,
    float fone) {
  __shared__ __align__(16) float ldsred[256];
  int tid = threadIdx.x;
  int gt = blockIdx.x * 256 + tid;
  int j = gt >> 5;
  int g = tid >> 5;
  int l = tid & 31;
  int eslot = l >> 2;
  int chunk = l & 3;
  float acc[8] = {0.f, 0.f, 0.f, 0.f, 0.f, 0.f, 0.f, 0.f};
  uint32_t e0 = 0, deg = 0;
  if (j < n) {
    e0 = rowp[j];
    deg = rowp[j + 1] - e0;
  }
  const half_t* hp = hs + (size_t)(chunk << 3);
  uint32_t base = 0;
  for (; base + 32 <= deg; base += 32) {
    uint32_t idx = esrc[e0 + base + (uint32_t)l];  // 128 B coalesced, 32 edges
#pragma unroll
    for (int k = 0; k < 32; k += 8) {
      uint32_t s = (uint32_t)__shfl((int)idx, k + eslot, 32);
      const half8 v = *(const half8*)(hp + ((size_t)s << 5));
#pragma unroll
      for (int q = 0; q < 8; ++q) acc[q] = fmaf((float)v[q], fone, acc[q]);
    }
  }
  if (base < deg) {
    uint32_t rem = deg - base;  // 1..31
    uint32_t li = (uint32_t)l < rem ? (uint32_t)l : rem - 1u;
    uint32_t idx = esrc[e0 + base + li];
    for (uint32_t k = 0; k < rem; k += 8) {
      uint32_t kk = k + (uint32_t)eslot;
      uint32_t ks = kk < rem ? kk : rem - 1u;
      uint32_t s = (uint32_t)__shfl((int)idx, (int)ks, 32);
      if (kk < rem) {
        const half8 v = *(const half8*)(hp + ((size_t)s << 5));
#pragma unroll
        for (int q = 0; q < 8; ++q) acc[q] = fmaf((float)v[q], fone, acc[q]);
      }
    }
  }
  // reduce across 8 edge slots (lane bits 2..4)
#pragma unroll
  for (int m = 4; m <= 16; m <<= 1) {
#pragma unroll
    for (int q = 0; q < 8; ++q) acc[q] += __shfl_xor(acc[q], m);
  }
  // lanes l<4 (eslot 0) hold the 8-dim sums for their chunk: park in LDS
  if (l < 4) {
    *(float4*)(&ldsred[(g << 5) + (chunk << 3) + 0]) =
        make_float4(acc[0], acc[1], acc[2], acc[3]);
    *(float4*)(&ldsred[(g << 5) + (chunk << 3) + 4]) =
        make_float4(acc[4], acc[5], acc[6], acc[7]);
  }
  __builtin_amdgcn_wave_barrier();
  if (j >= n) return;
  float sum = ldsred[(g << 5) + l];
  sum += (float)hs[(size_t)j * 32 + l];  // self-loop (already dinv[src]-scaled)
  float dj = dinv[j];
  float v = dj * sum;
  if (mode == 1) {
    v += bias[l];
    v = v > 0.f ? v : expm1f(v);
    outf[gt] = v;
  } else if (mode == 3) {
    v += bias[l];
    v = v > 0.f ? v : expm1f(v);
    v = tf_keep(k0, k1, (uint32_t)gt) ? v * 2.f : 0.f;
    v *= dj;
    outh[gt] = (half_t)v;
  } else {
    outf[gt] = v;
  }
}

// ---------------------------------------------------------------------------
extern "C" void kernel_launch(void* const* d_in, const int* in_sizes, int n_in,
                              void* d_out, int out_size, void* d_ws, size_t ws_size,
                              hipStream_t stream) {
  const float* x  = (const float*)d_in[0];
  const int*   ei = (const int*)d_in[1];
  const float* W1 = (const float*)d_in[2];
  const float* b1 = (const float*)d_in[3];
  const float* W2 = (const float*)d_in[4];
  const float* b2 = (const float*)d_in[5];
  const float* W3 = (const float*)d_in[6];
  const float* b3 = (const float*)d_in[7];
  float* out = (float*)d_out;

  const int n = in_sizes[0] / 64;
  const int E = in_sizes[1] / 2;
  const int* src = ei;
  const int* dst = ei + E;

  char* ws = (char*)d_ws;
  size_t off = 0;
  auto alloc = [&](size_t bytes) {
    void* p = ws + off;
    off = (off + bytes + 255) & ~(size_t)255;
    return p;
  };
  float*    A32   = (float*)alloc((size_t)n * 32 * 4);  // gather2 out / gemm2 in; aliased tbl
  float*    C     = (float*)alloc((size_t)n * 64 * 4);  // gemm2 out; aliased staging
  half_t*   A16   = (half_t*)alloc((size_t)n * 32 * 2); // fp16 row-major table
  half_t*   B16   = (half_t*)alloc((size_t)n * 32 * 2); // fp16 row-major table
  float*    dinv  = (float*)alloc((size_t)n * 4);
  uint32_t* rowp  = (uint32_t*)alloc((size_t)(n + 1) * 4);
  uint32_t* esrc  = (uint32_t*)alloc((size_t)E * 4);
  uint32_t* gbcnt = (uint32_t*)alloc(1024 * 4);
  uint32_t* bbase = (uint32_t*)alloc(1024 * 4);
  uint32_t* staging = (uint32_t*)C;    // C dead until layer 2
  uint32_t* tbl     = (uint32_t*)A32;  // A32 dead until gather2
  (void)ws_size; (void)n_in; (void)out_size;

  uint32_t k1a, k1b, k2a, k2b;
  tf2x32(0u, 42u, 0u, 0u, k1a, k1b);
  tf2x32(0u, 42u, 0u, 1u, k2a, k2b);

  const int NB   = (n + 127) >> 7;
  const int NBLK = (E + CHUNK - 1) / CHUNK;
  const int nv   = n * 32;
  const int gV   = (nv + 255) / 256;
  const int gG1  = (n + 31) / 32;
  const int gG2  = (n + 15) / 16;
  dim3 blk(256);

  // ---- CSR build ----
  zero1024<<<1, dim3(1024), 0, stream>>>(gbcnt);
  k4_binhist<<<NBLK, blk, 0, stream>>>(src, dst, tbl, gbcnt, staging, E, NB);
  k3_bscan<<<1, dim3(1024), 0, stream>>>(gbcnt, bbase, NB);
  k5_fin<<<NB, blk, 0, stream>>>(staging, tbl, bbase, rowp, dinv, esrc, n, E, NBLK, NB);

  // ---- layer 1: A16 = fp16(dinv*(x@W1)); gather -> B16 (fp16) ----
  gemm_n64_k32<<<gG1, blk, 0, stream>>>(x, W1, dinv, A16, n);
  gather_fin<<<gV, blk, 0, stream>>>(A16, rowp, esrc, dinv, b1, nullptr, B16, n, 3, k1a, k1b, 1.0f);

  // ---- layer 2: gather(B16) -> A32 (fp32); gemm2 -> C ----
  gather_fin<<<gV, blk, 0, stream>>>(B16, rowp, esrc, dinv, nullptr, A32, nullptr, n, 0, 0u, 0u, 1.0f);
  gemm_k32_n64_act<<<gG2, blk, 0, stream>>>(A32, W2, b2, C, k2a, k2b, n);

  // ---- layer 3: A16 = fp16(dinv*(C@W3)); gather -> out (fp32) ----
  gemm_n64_k32<<<gG1, blk, 0, stream>>>(C, W3, dinv, A16, n);
  gather_fin<<<gV, blk, 0, stream>>>(A16, rowp, esrc, dinv, b3, out, nullptr, n, 1, 0u, 0u, 1.0f);
}

// Round 13
// 329.293 us; speedup vs baseline: 1.2481x; 1.0157x over previous
//
#include <hip/hip_runtime.h>
#include <stdint.h>
#include <stddef.h>

typedef _Float16 half_t;
typedef _Float16 half4 __attribute__((ext_vector_type(4)));
typedef _Float16 half8 __attribute__((ext_vector_type(8)));

// ---------------------------------------------------------------------------
// JAX threefry2x32 (partitionable mode — verified: absmax 2.4e-4).
// ---------------------------------------------------------------------------
__host__ __device__ __forceinline__ uint32_t rotl32(uint32_t v, uint32_t r) {
  return (v << r) | (v >> (32u - r));
}

__host__ __device__ __forceinline__ void tf2x32(uint32_t k0, uint32_t k1,
                                                uint32_t x0, uint32_t x1,
                                                uint32_t& o0, uint32_t& o1) {
  uint32_t ks2 = k0 ^ k1 ^ 0x1BD11BDAu;
  x0 += k0; x1 += k1;
  x0 += x1; x1 = rotl32(x1, 13); x1 ^= x0;
  x0 += x1; x1 = rotl32(x1, 15); x1 ^= x0;
  x0 += x1; x1 = rotl32(x1, 26); x1 ^= x0;
  x0 += x1; x1 = rotl32(x1, 6);  x1 ^= x0;
  x0 += k1; x1 += ks2 + 1u;
  x0 += x1; x1 = rotl32(x1, 17); x1 ^= x0;
  x0 += x1; x1 = rotl32(x1, 29); x1 ^= x0;
  x0 += x1; x1 = rotl32(x1, 16); x1 ^= x0;
  x0 += x1; x1 = rotl32(x1, 24); x1 ^= x0;
  x0 += ks2; x1 += k0 + 2u;
  x0 += x1; x1 = rotl32(x1, 13); x1 ^= x0;
  x0 += x1; x1 = rotl32(x1, 15); x1 ^= x0;
  x0 += x1; x1 = rotl32(x1, 26); x1 ^= x0;
  x0 += x1; x1 = rotl32(x1, 6);  x1 ^= x0;
  x0 += k0; x1 += k1 + 3u;
  x0 += x1; x1 = rotl32(x1, 17); x1 ^= x0;
  x0 += x1; x1 = rotl32(x1, 29); x1 ^= x0;
  x0 += x1; x1 = rotl32(x1, 16); x1 ^= x0;
  x0 += x1; x1 = rotl32(x1, 24); x1 ^= x0;
  x0 += k1; x1 += ks2 + 4u;
  x0 += x1; x1 = rotl32(x1, 13); x1 ^= x0;
  x0 += x1; x1 = rotl32(x1, 15); x1 ^= x0;
  x0 += x1; x1 = rotl32(x1, 26); x1 ^= x0;
  x0 += x1; x1 = rotl32(x1, 6);  x1 ^= x0;
  x0 += ks2; x1 += k0 + 5u;
  o0 = x0; o1 = x1;
}

__device__ __forceinline__ bool tf_keep(uint32_t k0, uint32_t k1, uint32_t idx) {
  uint32_t o0, o1;
  tf2x32(k0, k1, 0u, idx, o0, o1);
  return ((o0 ^ o1) >> 31) == 0u;
}

// ---------------------------------------------------------------------------
// CSR build, chunk-major staging.
// ---------------------------------------------------------------------------
#define CHUNK 4096
#define STASH 5120

__global__ __launch_bounds__(1024) void zero1024(uint32_t* __restrict__ p) {
  p[threadIdx.x] = 0u;
}

__global__ __launch_bounds__(256) void k4_binhist(const int* __restrict__ src,
                                                  const int* __restrict__ dst,
                                                  uint32_t* __restrict__ tbl,
                                                  uint32_t* __restrict__ gbcnt,
                                                  uint32_t* __restrict__ staging,
                                                  int E, int NB) {
  __shared__ uint32_t lcur[1024];
  __shared__ uint32_t ls[256];
  __shared__ uint32_t stage[CHUNK];
  int tid = threadIdx.x;
  for (int i = tid; i < NB; i += 256) lcur[i] = 0u;
  __syncthreads();
  int base = blockIdx.x * CHUNK;
  int end = min(base + CHUNK, E);
  uint32_t dv[16], sv[16];
  int m = 0;
  for (int i = base + tid; i < end; i += 256) {
    dv[m] = (uint32_t)dst[i];
    sv[m] = (uint32_t)src[i];
    ++m;
  }
  for (int q = 0; q < m; ++q) atomicAdd(&lcur[dv[q] >> 7], 1u);
  __syncthreads();
  uint32_t carry = 0u;
  for (int seg = 0; seg < 1024; seg += 256) {
    int i = seg + tid;
    uint32_t v = (i < NB) ? lcur[i] : 0u;
    ls[tid] = v;
    __syncthreads();
    for (int off = 1; off < 256; off <<= 1) {
      uint32_t t = (tid >= off) ? ls[tid - off] : 0u;
      __syncthreads();
      if (tid >= off) ls[tid] += t;
      __syncthreads();
    }
    uint32_t excl = carry + ls[tid] - v;
    if (i < NB) {
      tbl[(size_t)blockIdx.x * NB + i] = (excl << 16) | v;
      if (v) atomicAdd(&gbcnt[i], v);
      lcur[i] = excl;
    }
    carry += ls[255];
    __syncthreads();
  }
  for (int q = 0; q < m; ++q) {
    uint32_t d = dv[q];
    uint32_t p = atomicAdd(&lcur[d >> 7], 1u);
    stage[p] = ((d & 127u) << 17) | sv[q];
  }
  __syncthreads();
  int cnt_total = end - base;
  uint32_t* outp = staging + (size_t)blockIdx.x * CHUNK;
  for (int i = tid; i < cnt_total; i += 256) outp[i] = stage[i];
}

__global__ __launch_bounds__(1024) void k3_bscan(const uint32_t* __restrict__ gbcnt,
                                                 uint32_t* __restrict__ bbase, int NB) {
  __shared__ uint32_t s[1024];
  int i = threadIdx.x;
  uint32_t v = (i < NB) ? gbcnt[i] : 0u;
  s[i] = v;
  __syncthreads();
  for (int off = 1; off < 1024; off <<= 1) {
    uint32_t t = (i >= off) ? s[i - off] : 0u;
    __syncthreads();
    if (i >= off) s[i] += t;
    __syncthreads();
  }
  if (i < NB) bbase[i] = s[i] - v;
}

// k5 v2: 1024 threads/block (2 blocks/CU resident -> up to 32 waves/CU),
// thread-per-entry phase 1 (binary search over LDS chunk-prefix) so the
// staging loads are independent and overlap instead of serializing.
__global__ __launch_bounds__(1024) void k5_fin(
    const uint32_t* __restrict__ staging, const uint32_t* __restrict__ tbl,
    const uint32_t* __restrict__ bbase, uint32_t* __restrict__ rowp,
    float* __restrict__ dinv, uint32_t* __restrict__ esrc,
    int n, int E, int NBLK, int NB) {
  __shared__ uint32_t loff[1024];
  __shared__ uint32_t P[1025];
  __shared__ uint32_t ls[1024];
  __shared__ uint32_t stash[STASH];
  __shared__ uint32_t lc[128];
  __shared__ uint32_t sc[128];
  __shared__ uint32_t lcur[128];
  int tid = threadIdx.x;
  int b = blockIdx.x;
  if (tid < 128) lc[tid] = 0u;
  // phase 0: load column b of tbl; 1024-wide exclusive scan of counts -> P
  uint32_t packed = (tid < NBLK) ? tbl[(size_t)tid * NB + b] : 0u;
  uint32_t v = packed & 0xFFFFu;
  loff[tid] = packed >> 16;
  ls[tid] = v;
  __syncthreads();
  for (int off = 1; off < 1024; off <<= 1) {
    uint32_t t = (tid >= off) ? ls[tid - off] : 0u;
    __syncthreads();
    if (tid >= off) ls[tid] += t;
    __syncthreads();
  }
  P[tid] = ls[tid] - v;  // exclusive
  if (tid == 1023) P[1024] = ls[1023];
  __syncthreads();
  uint32_t total = P[NBLK];  // NBLK <= 1024
  // phase 1: thread-per-entry — search chunk, load entry, stash, count node
  for (uint32_t q = (uint32_t)tid; q < total; q += 1024u) {
    int lo = 0, hi = NBLK;
    while (hi - lo > 1) {
      int mid = (lo + hi) >> 1;
      if (P[mid] <= q) lo = mid; else hi = mid;
    }
    uint32_t e = staging[(size_t)lo * CHUNK + loff[lo] + (q - P[lo])];
    if (q < (uint32_t)STASH) stash[q] = e;
    atomicAdd(&lc[e >> 17], 1u);
  }
  __syncthreads();
  // phase 2: node scan -> rowp, dinv, cursors
  uint32_t myc = (tid < 128) ? lc[tid] : 0u;
  if (tid < 128) sc[tid] = myc;
  __syncthreads();
  for (int off = 1; off < 128; off <<= 1) {
    uint32_t t = (tid < 128 && tid >= off) ? sc[tid - off] : 0u;
    __syncthreads();
    if (tid < 128 && tid >= off) sc[tid] += t;
    __syncthreads();
  }
  uint32_t s = bbase[b];
  if (tid < 128) {
    uint32_t gstart = s + sc[tid] - myc;
    int node = (b << 7) + tid;
    if (node < n) {
      rowp[node] = gstart;
      dinv[node] = 1.0f / sqrtf((float)(myc + 1u));
    }
    lcur[tid] = gstart;
  }
  if (b == 0 && tid == 0) rowp[n] = (uint32_t)E;
  __syncthreads();
  // phase 3: place from stash (order within a node is irrelevant)
  uint32_t lim = total < (uint32_t)STASH ? total : (uint32_t)STASH;
  for (uint32_t q = (uint32_t)tid; q < lim; q += 1024u) {
    uint32_t e = stash[q];
    uint32_t pos = atomicAdd(&lcur[e >> 17], 1u);
    esrc[pos] = e & 0x1FFFFu;
  }
  if (total > (uint32_t)STASH) {
    for (uint32_t q = (uint32_t)STASH + (uint32_t)tid; q < total; q += 1024u) {
      int lo = 0, hi = NBLK;
      while (hi - lo > 1) {
        int mid = (lo + hi) >> 1;
        if (P[mid] <= q) lo = mid; else hi = mid;
      }
      uint32_t e = staging[(size_t)lo * CHUNK + loff[lo] + (q - P[lo])];
      uint32_t pos = atomicAdd(&lcur[e >> 17], 1u);
      esrc[pos] = e & 0x1FFFFu;
    }
  }
}

// ---------------------------------------------------------------------------
// GEMM: out16[n,32] = fp16( dinv[row] * (X[n,64] @ W[64,32]) )  (row-major).
// ---------------------------------------------------------------------------
__global__ __launch_bounds__(256) void gemm_n64_k32(
    const float* __restrict__ X, const float* __restrict__ W,
    const float* __restrict__ dinv, half_t* __restrict__ out16, int n) {
  __shared__ float Ws[64 * 32];
  __shared__ float Xs[32 * 68];
  int tid = threadIdx.x;
  {
    const float4* Wv = (const float4*)W;
    float4* Wsv = (float4*)Ws;
    Wsv[tid] = Wv[tid];
    Wsv[tid + 256] = Wv[tid + 256];
  }
  int row0 = blockIdx.x * 32;
  {
    const float4* Xv = (const float4*)(X + (size_t)row0 * 64);
    int lim = (n - row0) * 16;
    float4 z = make_float4(0.f, 0.f, 0.f, 0.f);
    int i0 = tid, i1 = tid + 256;
    float4 v0 = (i0 < lim) ? Xv[i0] : z;
    float4 v1 = (i1 < lim) ? Xv[i1] : z;
    *(float4*)(Xs + (i0 >> 4) * 68 + ((i0 & 15) << 2)) = v0;
    *(float4*)(Xs + (i1 >> 4) * 68 + ((i1 & 15) << 2)) = v1;
  }
  __syncthreads();
  int r = tid >> 3;
  int c4 = (tid & 7) << 2;
  int row = row0 + r;
  if (row >= n) return;
  float4 acc = make_float4(0.f, 0.f, 0.f, 0.f);
#pragma unroll
  for (int k = 0; k < 64; k += 4) {
    float4 xv = *(const float4*)(Xs + r * 68 + k);
    float4 w0 = *(const float4*)(Ws + (k + 0) * 32 + c4);
    float4 w1 = *(const float4*)(Ws + (k + 1) * 32 + c4);
    float4 w2 = *(const float4*)(Ws + (k + 2) * 32 + c4);
    float4 w3 = *(const float4*)(Ws + (k + 3) * 32 + c4);
    acc.x = fmaf(xv.x, w0.x, acc.x); acc.y = fmaf(xv.x, w0.y, acc.y);
    acc.z = fmaf(xv.x, w0.z, acc.z); acc.w = fmaf(xv.x, w0.w, acc.w);
    acc.x = fmaf(xv.y, w1.x, acc.x); acc.y = fmaf(xv.y, w1.y, acc.y);
    acc.z = fmaf(xv.y, w1.z, acc.z); acc.w = fmaf(xv.y, w1.w, acc.w);
    acc.x = fmaf(xv.z, w2.x, acc.x); acc.y = fmaf(xv.z, w2.y, acc.y);
    acc.z = fmaf(xv.z, w2.z, acc.z); acc.w = fmaf(xv.z, w2.w, acc.w);
    acc.x = fmaf(xv.w, w3.x, acc.x); acc.y = fmaf(xv.w, w3.y, acc.y);
    acc.z = fmaf(xv.w, w3.z, acc.z); acc.w = fmaf(xv.w, w3.w, acc.w);
  }
  float dj = dinv[row];
  half4 h;
  h.x = (half_t)(acc.x * dj); h.y = (half_t)(acc.y * dj);
  h.z = (half_t)(acc.z * dj); h.w = (half_t)(acc.w * dj);
  *(half4*)(out16 + (size_t)row * 32 + c4) = h;
}

// ---------------------------------------------------------------------------
// GEMM: out[n,64] = dropout(celu(X[n,32] @ W[32,64] + b))  (fp32 in/out).
// ---------------------------------------------------------------------------
__global__ __launch_bounds__(256) void gemm_k32_n64_act(
    const float* __restrict__ X, const float* __restrict__ W,
    const float* __restrict__ bias, float* __restrict__ out,
    uint32_t k0, uint32_t k1, int n) {
  __shared__ float Ws[32 * 64];
  __shared__ float Xs[16 * 36];
  int tid = threadIdx.x;
  {
    const float4* Wv = (const float4*)W;
    float4* Wsv = (float4*)Ws;
    Wsv[tid] = Wv[tid];
    Wsv[tid + 256] = Wv[tid + 256];
  }
  int row0 = blockIdx.x * 16;
  if (tid < 128) {
    const float4* Xv = (const float4*)(X + (size_t)row0 * 32);
    int lim = (n - row0) * 8;
    float4 z = make_float4(0.f, 0.f, 0.f, 0.f);
    float4 v = (tid < lim) ? Xv[tid] : z;
    *(float4*)(Xs + (tid >> 3) * 36 + ((tid & 7) << 2)) = v;
  }
  __syncthreads();
  int r = tid >> 4;
  int c4 = (tid & 15) << 2;
  int row = row0 + r;
  if (row >= n) return;
  float4 acc = make_float4(0.f, 0.f, 0.f, 0.f);
#pragma unroll
  for (int k = 0; k < 32; k += 4) {
    float4 xv = *(const float4*)(Xs + r * 36 + k);
    float4 w0 = *(const float4*)(Ws + (k + 0) * 64 + c4);
    float4 w1 = *(const float4*)(Ws + (k + 1) * 64 + c4);
    float4 w2 = *(const float4*)(Ws + (k + 2) * 64 + c4);
    float4 w3 = *(const float4*)(Ws + (k + 3) * 64 + c4);
    acc.x = fmaf(xv.x, w0.x, acc.x); acc.y = fmaf(xv.x, w0.y, acc.y);
    acc.z = fmaf(xv.x, w0.z, acc.z); acc.w = fmaf(xv.x, w0.w, acc.w);
    acc.x = fmaf(xv.y, w1.x, acc.x); acc.y = fmaf(xv.y, w1.y, acc.y);
    acc.z = fmaf(xv.y, w1.z, acc.z); acc.w = fmaf(xv.y, w1.w, acc.w);
    acc.x = fmaf(xv.z, w2.x, acc.x); acc.y = fmaf(xv.z, w2.y, acc.y);
    acc.z = fmaf(xv.z, w2.z, acc.z); acc.w = fmaf(xv.z, w2.w, acc.w);
    acc.x = fmaf(xv.w, w3.x, acc.x); acc.y = fmaf(xv.w, w3.y, acc.y);
    acc.z = fmaf(xv.w, w3.z, acc.z); acc.w = fmaf(xv.w, w3.w, acc.w);
  }
  float4 bv = *(const float4*)(bias + c4);
  float vv[4] = {acc.x + bv.x, acc.y + bv.y, acc.z + bv.z, acc.w + bv.w};
  uint32_t base = (uint32_t)row * 64u + (uint32_t)c4;
#pragma unroll
  for (int q = 0; q < 4; ++q) {
    float v = vv[q];
    v = v > 0.f ? v : expm1f(v);
    vv[q] = tf_keep(k0, k1, base + q) ? v * 2.f : 0.f;
  }
  *(float4*)(out + (size_t)row * 64 + c4) = make_float4(vv[0], vv[1], vv[2], vv[3]);
}

// ---------------------------------------------------------------------------
// Gather-reduce v6 (unchanged from R12): row-major fp16 table, half8 loads,
// 8 eslots x 4 chunks, LDS-park epilogue.
// ---------------------------------------------------------------------------
__global__ __launch_bounds__(256) void gather_fin(
    const half_t* __restrict__ hs, const uint32_t* __restrict__ rowp,
    const uint32_t* __restrict__ esrc, const float* __restrict__ dinv,
    const float* __restrict__ bias, float* __restrict__ outf,
    half_t* __restrict__ outh, int n, int mode, uint32_t k0, uint32_t k1,
    float fone) {
  __shared__ __align__(16) float ldsred[256];
  int tid = threadIdx.x;
  int gt = blockIdx.x * 256 + tid;
  int j = gt >> 5;
  int g = tid >> 5;
  int l = tid & 31;
  int eslot = l >> 2;
  int chunk = l & 3;
  float acc[8] = {0.f, 0.f, 0.f, 0.f, 0.f, 0.f, 0.f, 0.f};
  uint32_t e0 = 0, deg = 0;
  if (j < n) {
    e0 = rowp[j];
    deg = rowp[j + 1] - e0;
  }
  const half_t* hp = hs + (size_t)(chunk << 3);
  uint32_t base = 0;
  for (; base + 32 <= deg; base += 32) {
    uint32_t idx = esrc[e0 + base + (uint32_t)l];
#pragma unroll
    for (int k = 0; k < 32; k += 8) {
      uint32_t s = (uint32_t)__shfl((int)idx, k + eslot, 32);
      const half8 v = *(const half8*)(hp + ((size_t)s << 5));
#pragma unroll
      for (int q = 0; q < 8; ++q) acc[q] = fmaf((float)v[q], fone, acc[q]);
    }
  }
  if (base < deg) {
    uint32_t rem = deg - base;
    uint32_t li = (uint32_t)l < rem ? (uint32_t)l : rem - 1u;
    uint32_t idx = esrc[e0 + base + li];
    for (uint32_t k = 0; k < rem; k += 8) {
      uint32_t kk = k + (uint32_t)eslot;
      uint32_t ks = kk < rem ? kk : rem - 1u;
      uint32_t s = (uint32_t)__shfl((int)idx, (int)ks, 32);
      if (kk < rem) {
        const half8 v = *(const half8*)(hp + ((size_t)s << 5));
#pragma unroll
        for (int q = 0; q < 8; ++q) acc[q] = fmaf((float)v[q], fone, acc[q]);
      }
    }
  }
#pragma unroll
  for (int m = 4; m <= 16; m <<= 1) {
#pragma unroll
    for (int q = 0; q < 8; ++q) acc[q] += __shfl_xor(acc[q], m);
  }
  if (l < 4) {
    *(float4*)(&ldsred[(g << 5) + (chunk << 3) + 0]) =
        make_float4(acc[0], acc[1], acc[2], acc[3]);
    *(float4*)(&ldsred[(g << 5) + (chunk << 3) + 4]) =
        make_float4(acc[4], acc[5], acc[6], acc[7]);
  }
  __builtin_amdgcn_wave_barrier();
  if (j >= n) return;
  float sum = ldsred[(g << 5) + l];
  sum += (float)hs[(size_t)j * 32 + l];
  float dj = dinv[j];
  float v = dj * sum;
  if (mode == 1) {
    v += bias[l];
    v = v > 0.f ? v : expm1f(v);
    outf[gt] = v;
  } else if (mode == 3) {
    v += bias[l];
    v = v > 0.f ? v : expm1f(v);
    v = tf_keep(k0, k1, (uint32_t)gt) ? v * 2.f : 0.f;
    v *= dj;
    outh[gt] = (half_t)v;
  } else {
    outf[gt] = v;
  }
}

// ---------------------------------------------------------------------------
extern "C" void kernel_launch(void* const* d_in, const int* in_sizes, int n_in,
                              void* d_out, int out_size, void* d_ws, size_t ws_size,
                              hipStream_t stream) {
  const float* x  = (const float*)d_in[0];
  const int*   ei = (const int*)d_in[1];
  const float* W1 = (const float*)d_in[2];
  const float* b1 = (const float*)d_in[3];
  const float* W2 = (const float*)d_in[4];
  const float* b2 = (const float*)d_in[5];
  const float* W3 = (const float*)d_in[6];
  const float* b3 = (const float*)d_in[7];
  float* out = (float*)d_out;

  const int n = in_sizes[0] / 64;
  const int E = in_sizes[1] / 2;
  const int* src = ei;
  const int* dst = ei + E;

  char* ws = (char*)d_ws;
  size_t off = 0;
  auto alloc = [&](size_t bytes) {
    void* p = ws + off;
    off = (off + bytes + 255) & ~(size_t)255;
    return p;
  };
  float*    A32   = (float*)alloc((size_t)n * 32 * 4);  // gather2 out / gemm2 in; aliased tbl
  float*    C     = (float*)alloc((size_t)n * 64 * 4);  // gemm2 out; aliased staging
  half_t*   A16   = (half_t*)alloc((size_t)n * 32 * 2); // fp16 row-major table
  half_t*   B16   = (half_t*)alloc((size_t)n * 32 * 2); // fp16 row-major table
  float*    dinv  = (float*)alloc((size_t)n * 4);
  uint32_t* rowp  = (uint32_t*)alloc((size_t)(n + 1) * 4);
  uint32_t* esrc  = (uint32_t*)alloc((size_t)E * 4);
  uint32_t* gbcnt = (uint32_t*)alloc(1024 * 4);
  uint32_t* bbase = (uint32_t*)alloc(1024 * 4);
  uint32_t* staging = (uint32_t*)C;    // C dead until layer 2
  uint32_t* tbl     = (uint32_t*)A32;  // A32 dead until gather2
  (void)ws_size; (void)n_in; (void)out_size;

  uint32_t k1a, k1b, k2a, k2b;
  tf2x32(0u, 42u, 0u, 0u, k1a, k1b);
  tf2x32(0u, 42u, 0u, 1u, k2a, k2b);

  const int NB   = (n + 127) >> 7;
  const int NBLK = (E + CHUNK - 1) / CHUNK;
  const int nv   = n * 32;
  const int gV   = (nv + 255) / 256;
  const int gG1  = (n + 31) / 32;
  const int gG2  = (n + 15) / 16;
  dim3 blk(256);

  // ---- CSR build ----
  zero1024<<<1, dim3(1024), 0, stream>>>(gbcnt);
  k4_binhist<<<NBLK, blk, 0, stream>>>(src, dst, tbl, gbcnt, staging, E, NB);
  k3_bscan<<<1, dim3(1024), 0, stream>>>(gbcnt, bbase, NB);
  k5_fin<<<NB, dim3(1024), 0, stream>>>(staging, tbl, bbase, rowp, dinv, esrc, n, E, NBLK, NB);

  // ---- layer 1: A16 = fp16(dinv*(x@W1)); gather -> B16 (fp16) ----
  gemm_n64_k32<<<gG1, blk, 0, stream>>>(x, W1, dinv, A16, n);
  gather_fin<<<gV, blk, 0, stream>>>(A16, rowp, esrc, dinv, b1, nullptr, B16, n, 3, k1a, k1b, 1.0f);

  // ---- layer 2: gather(B16) -> A32 (fp32); gemm2 -> C ----
  gather_fin<<<gV, blk, 0, stream>>>(B16, rowp, esrc, dinv, nullptr, A32, nullptr, n, 0, 0u, 0u, 1.0f);
  gemm_k32_n64_act<<<gG2, blk, 0, stream>>>(A32, W2, b2, C, k2a, k2b, n);

  // ---- layer 3: A16 = fp16(dinv*(C@W3)); gather -> out (fp32) ----
  gemm_n64_k32<<<gG1, blk, 0, stream>>>(C, W3, dinv, A16, n);
  gather_fin<<<gV, blk, 0, stream>>>(A16, rowp, esrc, dinv, b3, out, nullptr, n, 1, 0u, 0u, 1.0f);
}